// Round 2
// baseline (419.989 us; speedup 1.0000x reference)
//
#include <hip/hip_runtime.h>
#include <hip/hip_fp16.h>

// ---------------------------------------------------------------------------
// GCN pipeline. Round 15:
//  - fused_csr: scan1+scan2+finalize+reorder in ONE kernel (196 co-resident
//    blocks, software grid barrier x2). reorder recomputes ex/norm inline
//    (bit-identical op sequence) so finalize+reorder share a phase.
//  - gather: em-load software pipeline (prefetch next 8-edge batch during
//    row loads) -- hides the L2 em latency level of the chain.
//  - pool_head: pool + grid barrier + head in one kernel (391 blocks).
//  - RANK TRICK + fused GEMM-1/hist overlap (round 14) retained.
//  - GEMM: LDS-staged bf16x3 MFMA, frag-ordered W, fp16 out (unchanged)
// ---------------------------------------------------------------------------

typedef short bf16x8 __attribute__((ext_vector_type(8)));
typedef float f32x4  __attribute__((ext_vector_type(4)));

__device__ inline unsigned short f2bf_rne(float f) {
    unsigned u = __float_as_uint(f);
    unsigned r = (u + 0x7fffu + ((u >> 16) & 1u)) >> 16;
    return (unsigned short)r;
}
__device__ inline float bf2f(unsigned short h) {
    return __uint_as_float(((unsigned)h) << 16);
}

// software grid barrier: requires all blocks co-resident (grid <= capacity)
__device__ inline void gbar(int* cnt, int* gen, int nblk) {
    __threadfence();
    __syncthreads();
    if (threadIdx.x == 0) {
        int g = __hip_atomic_load(gen, __ATOMIC_RELAXED, __HIP_MEMORY_SCOPE_AGENT);
        if (__hip_atomic_fetch_add(cnt, 1, __ATOMIC_ACQ_REL, __HIP_MEMORY_SCOPE_AGENT) == nblk - 1) {
            __hip_atomic_store(cnt, 0, __ATOMIC_RELAXED, __HIP_MEMORY_SCOPE_AGENT);
            __hip_atomic_store(gen, g + 1, __ATOMIC_RELEASE, __HIP_MEMORY_SCOPE_AGENT);
        } else {
            while (__hip_atomic_load(gen, __ATOMIC_ACQUIRE, __HIP_MEMORY_SCOPE_AGENT) == g) {
                __builtin_amdgcn_s_sleep(1);
            }
        }
    }
    __syncthreads();
    __threadfence();
}

// ---- dispatch #1: weight split/transpose + zero(count, pooled, cnt, sync)
// frag addr = ((ct*4+ks)*64 + (q*16+nn))*8 + j ; n=ct*16+nn, k=ks*32+q*8+j
__global__ __launch_bounds__(256) void wconv_zero(const float* __restrict__ W1,
                                                  const float* __restrict__ W2,
                                                  unsigned short* __restrict__ W1h,
                                                  unsigned short* __restrict__ W1l,
                                                  unsigned short* __restrict__ W2h,
                                                  unsigned short* __restrict__ W2l,
                                                  int* __restrict__ count,
                                                  float* __restrict__ pooled,
                                                  float* __restrict__ cnt,
                                                  int* __restrict__ sync, int N) {
    int tid = threadIdx.x;
    int b = blockIdx.x;
    if (b < 128) {
        int i = b * 256 + tid;               // 0..32767
        const float* W = (i < 16384) ? W1 : W2;
        unsigned short* Wh = (i < 16384) ? W1h : W2h;
        unsigned short* Wl = (i < 16384) ? W1l : W2l;
        int ii = i & 16383;
        int k = ii >> 7, n = ii & 127;
        float v = W[ii];
        unsigned short h = f2bf_rne(v);
        float lo = v - bf2f(h);
        int ct = n >> 4, nn = n & 15, ks = k >> 5, q = (k >> 3) & 3, j = k & 7;
        int oidx = (((ct * 4 + ks) * 64) + (q * 16 + nn)) * 8 + j;
        Wh[oidx] = h;
        Wl[oidx] = f2bf_rne(lo);
    } else {
        int idx = (b - 128) * 256 + tid;
        if (idx < N) count[idx] = 0;
        else if (idx < N + 8192) pooled[idx - N] = 0.f;
        else if (idx < N + 8256) cnt[idx - N - 8192] = 0.f;
        else if (idx < N + 8260) sync[idx - N - 8256] = 0;
    }
}

// ---- GEMM body: OUT_fp16[M,128] = act(X_f32) @ W via bf16x3 MFMA --------
template <bool RELU_IN>
__device__ __forceinline__ void gemm_body(const float* __restrict__ X,
                                          const unsigned short* __restrict__ Wfh,
                                          const unsigned short* __restrict__ Wfl,
                                          __half* __restrict__ OUT, int M, int blk) {
    __shared__ unsigned short Xh[64][136];
    __shared__ unsigned short Xl[64][136];
    int tid = threadIdx.x;
    int w = tid >> 6, l = tid & 63;
    int m0 = blk * 64;

#pragma unroll
    for (int it = 0; it < 8; it++) {
        int i = tid + it * 256;
        int row = i >> 5, c4 = i & 31;
        int grow = m0 + row;
        float4 v = make_float4(0.f, 0.f, 0.f, 0.f);
        if (grow < M) v = *(const float4*)(X + (size_t)grow * 128 + c4 * 4);
        if (RELU_IN) {
            v.x = fmaxf(v.x, 0.f); v.y = fmaxf(v.y, 0.f);
            v.z = fmaxf(v.z, 0.f); v.w = fmaxf(v.w, 0.f);
        }
        float a[4] = {v.x, v.y, v.z, v.w};
        ushort4 hi, lo;
        unsigned short* hp = (unsigned short*)&hi;
        unsigned short* lp = (unsigned short*)&lo;
#pragma unroll
        for (int e = 0; e < 4; e++) {
            unsigned short h = f2bf_rne(a[e]);
            hp[e] = h;
            lp[e] = f2bf_rne(a[e] - bf2f(h));
        }
        *(ushort4*)&Xh[row][c4 * 4] = hi;
        *(ushort4*)&Xl[row][c4 * 4] = lo;
    }
    __syncthreads();

    int q = l >> 4, nn = l & 15;
    f32x4 acc[8];
#pragma unroll
    for (int ct = 0; ct < 8; ct++) acc[ct] = (f32x4){0.f, 0.f, 0.f, 0.f};

#pragma unroll
    for (int ks = 0; ks < 4; ks++) {
        bf16x8 ahi = *(const bf16x8*)&Xh[w * 16 + nn][ks * 32 + q * 8];
        bf16x8 alo = *(const bf16x8*)&Xl[w * 16 + nn][ks * 32 + q * 8];
#pragma unroll
        for (int ct = 0; ct < 8; ct++) {
            size_t fo = ((size_t)(ct * 4 + ks) * 64 + l) * 8;
            bf16x8 bhi = *(const bf16x8*)(Wfh + fo);
            bf16x8 blo = *(const bf16x8*)(Wfl + fo);
            acc[ct] = __builtin_amdgcn_mfma_f32_16x16x32_bf16(ahi, bhi, acc[ct], 0, 0, 0);
            acc[ct] = __builtin_amdgcn_mfma_f32_16x16x32_bf16(alo, bhi, acc[ct], 0, 0, 0);
            acc[ct] = __builtin_amdgcn_mfma_f32_16x16x32_bf16(ahi, blo, acc[ct], 0, 0, 0);
        }
    }
    __syncthreads();   // done with Xh — reuse as fp16 epilogue buffer

#pragma unroll
    for (int r = 0; r < 4; r++) {
        int lrow = w * 16 + q * 4 + r;
#pragma unroll
        for (int ct = 0; ct < 8; ct++) {
            __half hv = __float2half(acc[ct][r]);
            Xh[lrow][ct * 16 + nn] = __half_as_ushort(hv);
        }
    }
    __syncthreads();
#pragma unroll
    for (int t = 0; t < 4; t++) {
        int c = tid + t * 256;
        int row = c >> 4, seg = c & 15;
        int grow = m0 + row;
        if (grow < M) {
            uint4 v = *(uint4*)&Xh[row][seg * 8];
            *(uint4*)((unsigned short*)OUT + (size_t)grow * 128 + seg * 8) = v;
        }
    }
}

// layer-2 GEMM (relu fused in staging)
__global__ __launch_bounds__(256) void gemm_mfma_relu(const float* __restrict__ X,
                                                      const unsigned short* __restrict__ Wfh,
                                                      const unsigned short* __restrict__ Wfl,
                                                      __half* __restrict__ OUT, int M) {
    gemm_body<true>(X, Wfh, Wfl, OUT, M, blockIdx.x);
}

// fat kernel: blocks [0,gblocks) = GEMM-1, blocks [gblocks,..) = hist+rank.
__global__ __launch_bounds__(256) void fused_hg(const float* __restrict__ X,
                                                const unsigned short* __restrict__ Wfh,
                                                const unsigned short* __restrict__ Wfl,
                                                __half* __restrict__ OUT, int M, int gblocks,
                                                const int* __restrict__ dst,
                                                int* __restrict__ count,
                                                int* __restrict__ rank, int E) {
    if ((int)blockIdx.x < gblocks) {
        gemm_body<false>(X, Wfh, Wfl, OUT, M, blockIdx.x);
    } else {
        int e = ((int)blockIdx.x - gblocks) * 256 + (int)threadIdx.x;
        if (e < E) {
            int d = dst[e];
            rank[e] = atomicAdd(&count[d], 1);   // rank within dst bucket
        }
    }
}

// ---- fused CSR: tile-scan -> gbar -> block-sum scan -> gbar ->
//      {rowptr+dinv, reorder} in one phase. grid = nb blocks (co-resident).
__global__ __launch_bounds__(256) void fused_csr(const int* __restrict__ count,
                                                 int* __restrict__ tmp,
                                                 int* __restrict__ bsum,
                                                 int* __restrict__ boff,
                                                 int* __restrict__ rowptr,
                                                 float* __restrict__ dinv,
                                                 const int* __restrict__ src,
                                                 const int* __restrict__ dst,
                                                 const int* __restrict__ rank,
                                                 int2* __restrict__ em,
                                                 int* __restrict__ sync,
                                                 int N, int E, int nb) {
    int tid = threadIdx.x;
    int b = blockIdx.x;
    __shared__ int s[256];

    // phase 1: per-tile inclusive scan of count
    {
        int i = b * 256 + tid;
        int v = (i < N) ? count[i] : 0;
        s[tid] = v;
        __syncthreads();
#pragma unroll
        for (int off = 1; off < 256; off <<= 1) {
            int t = (tid >= off) ? s[tid - off] : 0;
            __syncthreads();
            s[tid] += t;
            __syncthreads();
        }
        if (i < N) tmp[i] = s[tid];
        if (tid == 255) bsum[b] = s[255];
    }
    gbar(&sync[0], &sync[1], nb);

    // phase 2: block 0 exclusive-scans block sums
    if (b == 0) {
        int v = (tid < nb) ? bsum[tid] : 0;
        s[tid] = v;
        __syncthreads();
#pragma unroll
        for (int off = 1; off < 256; off <<= 1) {
            int t = (tid >= off) ? s[tid - off] : 0;
            __syncthreads();
            s[tid] += t;
            __syncthreads();
        }
        if (tid < nb) boff[tid] = s[tid] - v;   // exclusive
    }
    gbar(&sync[0], &sync[1], nb);

    // phase 3a: rowptr (exclusive) + dinv
    for (int i = b * 256 + tid; i <= N; i += nb * 256) {
        int ex = (i == 0) ? 0 : tmp[i - 1] + boff[(i - 1) >> 8];
        rowptr[i] = ex;
        if (i < N) dinv[i] = 1.0f / sqrtf((float)count[i] + 1.0f);
    }
    // phase 3b: atomic-free scatter (ex/norm recomputed inline, bit-identical)
    for (int e = b * 256 + tid; e < E; e += nb * 256) {
        int sv = src[e], d = dst[e];
        int ex = (d == 0) ? 0 : tmp[d - 1] + boff[(d - 1) >> 8];
        int pos = ex + rank[e];
        float ds = 1.0f / sqrtf((float)count[sv] + 1.0f);
        float dd = 1.0f / sqrtf((float)count[d] + 1.0f);
        float norm = ds * dd;
        em[pos] = make_int2(sv, __float_as_int(norm));
    }
}

// process one batch of 8 edges (row loads + fma)
#define BATCH8(va0, va1, va2, va3, va4, va5, va6, va7)                          \
    do {                                                                        \
        float2 r0 = __half22float2(hp[(size_t)(int)(va0) * 64 + lane]);         \
        float2 r1 = __half22float2(hp[(size_t)(int)(va1) * 64 + lane]);         \
        float2 r2 = __half22float2(hp[(size_t)(int)(va2) * 64 + lane]);         \
        float2 r3 = __half22float2(hp[(size_t)(int)(va3) * 64 + lane]);         \
        float2 r4 = __half22float2(hp[(size_t)(int)(va4) * 64 + lane]);         \
        float2 r5 = __half22float2(hp[(size_t)(int)(va5) * 64 + lane]);         \
        float2 r6 = __half22float2(hp[(size_t)(int)(va6) * 64 + lane]);         \
        float2 r7 = __half22float2(hp[(size_t)(int)(va7) * 64 + lane]);         \
        float n0 = __int_as_float((int)((va0) >> 32));                          \
        float n1 = __int_as_float((int)((va1) >> 32));                          \
        float n2 = __int_as_float((int)((va2) >> 32));                          \
        float n3 = __int_as_float((int)((va3) >> 32));                          \
        float n4 = __int_as_float((int)((va4) >> 32));                          \
        float n5 = __int_as_float((int)((va5) >> 32));                          \
        float n6 = __int_as_float((int)((va6) >> 32));                          \
        float n7 = __int_as_float((int)((va7) >> 32));                          \
        ax = fmaf(r0.x, n0, ax); ay = fmaf(r0.y, n0, ay);                       \
        ax = fmaf(r1.x, n1, ax); ay = fmaf(r1.y, n1, ay);                       \
        ax = fmaf(r2.x, n2, ax); ay = fmaf(r2.y, n2, ay);                       \
        ax = fmaf(r3.x, n3, ax); ay = fmaf(r3.y, n3, ay);                       \
        ax = fmaf(r4.x, n4, ax); ay = fmaf(r4.y, n4, ay);                       \
        ax = fmaf(r5.x, n5, ax); ay = fmaf(r5.y, n5, ay);                       \
        ax = fmaf(r6.x, n6, ax); ay = fmaf(r6.y, n6, ay);                       \
        ax = fmaf(r7.x, n7, ax); ay = fmaf(r7.y, n7, ay);                       \
    } while (0)

// ---- gather: wave/node, fp16 operand, fp32 accum/out, em-prefetch pipe --
__global__ __launch_bounds__(256) void gather_half(const __half* __restrict__ h,
                                                   const float* __restrict__ dinv,
                                                   const float* __restrict__ bias,
                                                   const int* __restrict__ rowptr,
                                                   const long long* __restrict__ em,
                                                   float* __restrict__ B, int N) {
    int n = blockIdx.x * 4 + (threadIdx.x >> 6);
    int lane = threadIdx.x & 63;
    if (n >= N) return;
    int beg = rowptr[n], end = rowptr[n + 1];
    float din = dinv[n];
    const __half2* hp = (const __half2*)h;        // [N*64]
    float2 hv = __half22float2(hp[(size_t)n * 64 + lane]);
    float sw = din * din;
    float ax = hv.x * sw, ay = hv.y * sw;
    int j = beg;
    if (j + 8 <= end) {
        long long v0 = em[j],     v1 = em[j + 1], v2 = em[j + 2], v3 = em[j + 3];
        long long v4 = em[j + 4], v5 = em[j + 5], v6 = em[j + 6], v7 = em[j + 7];
        for (; j + 16 <= end; j += 8) {
            // prefetch next batch's em while current rows are in flight
            long long w0 = em[j + 8],  w1 = em[j + 9],  w2 = em[j + 10], w3 = em[j + 11];
            long long w4 = em[j + 12], w5 = em[j + 13], w6 = em[j + 14], w7 = em[j + 15];
            BATCH8(v0, v1, v2, v3, v4, v5, v6, v7);
            v0 = w0; v1 = w1; v2 = w2; v3 = w3;
            v4 = w4; v5 = w5; v6 = w6; v7 = w7;
        }
        BATCH8(v0, v1, v2, v3, v4, v5, v6, v7);
        j += 8;
    }
    for (; j + 4 <= end; j += 4) {
        long long v0 = em[j], v1 = em[j + 1], v2 = em[j + 2], v3 = em[j + 3];
        float2 r0 = __half22float2(hp[(size_t)(int)v0 * 64 + lane]);
        float2 r1 = __half22float2(hp[(size_t)(int)v1 * 64 + lane]);
        float2 r2 = __half22float2(hp[(size_t)(int)v2 * 64 + lane]);
        float2 r3 = __half22float2(hp[(size_t)(int)v3 * 64 + lane]);
        float n0 = __int_as_float((int)(v0 >> 32));
        float n1 = __int_as_float((int)(v1 >> 32));
        float n2 = __int_as_float((int)(v2 >> 32));
        float n3 = __int_as_float((int)(v3 >> 32));
        ax = fmaf(r0.x, n0, ax); ay = fmaf(r0.y, n0, ay);
        ax = fmaf(r1.x, n1, ax); ay = fmaf(r1.y, n1, ay);
        ax = fmaf(r2.x, n2, ax); ay = fmaf(r2.y, n2, ay);
        ax = fmaf(r3.x, n3, ax); ay = fmaf(r3.y, n3, ay);
    }
    for (; j < end; j++) {
        long long v = em[j];
        float2 r = __half22float2(hp[(size_t)(int)v * 64 + lane]);
        float nr = __int_as_float((int)(v >> 32));
        ax = fmaf(r.x, nr, ax); ay = fmaf(r.y, nr, ay);
    }
    float2 o;
    o.x = ax + bias[lane * 2];
    o.y = ay + bias[lane * 2 + 1];
    *(float2*)(B + (size_t)n * 128 + lane * 2) = o;
}

// ---- pool (run-length) + grid barrier + head, one kernel ----------------
__global__ __launch_bounds__(256) void pool_head(const float* __restrict__ B,
                                                 const int* __restrict__ batch,
                                                 float* pooled, float* cnt,
                                                 const float* __restrict__ Wfc1,
                                                 const float* __restrict__ bfc1,
                                                 const float* __restrict__ Wfc2,
                                                 const float* __restrict__ bfc2,
                                                 float* __restrict__ out,
                                                 int* __restrict__ sync,
                                                 int N, int nblk) {
    int c = threadIdx.x & 127;
    int half = threadIdx.x >> 7;
    int n0 = blockIdx.x * 128;
    float acc = 0.f, cacc = 0.f;
    int curg = -1;
    for (int i = half; i < 128; i += 2) {
        int n = n0 + i;
        if (n >= N) break;
        int g = batch[n];
        float v = fmaxf(B[(size_t)n * 128 + c], 0.f);
        if (g != curg) {
            if (curg >= 0) {
                atomicAdd(&pooled[curg * 128 + c], acc);
                if (c == 0) atomicAdd(&cnt[curg], cacc);
            }
            curg = g; acc = 0.f; cacc = 0.f;
        }
        acc += v; cacc += 1.f;
    }
    if (curg >= 0) {
        atomicAdd(&pooled[curg * 128 + c], acc);
        if (c == 0) atomicAdd(&cnt[curg], cacc);
    }

    gbar(&sync[2], &sync[3], nblk);

    int g = blockIdx.x;
    if (g < 64) {
        __shared__ float mean[128];
        int t = threadIdx.x;
        float inv = 1.0f / fmaxf(cnt[g], 1.0f);
        if (t < 128) mean[t] = pooled[g * 128 + t] * inv;
        __syncthreads();
        if (t < 64) {
            float s = bfc1[t];
#pragma unroll 4
            for (int k = 0; k < 128; k++) s = fmaf(mean[k], Wfc1[k * 64 + t], s);
            float p = fmaxf(s, 0.f) * Wfc2[t];
#pragma unroll
            for (int o = 32; o > 0; o >>= 1) p += __shfl_down(p, o, 64);
            if (t == 0) out[g] = p + bfc2[0];
        }
    }
}

extern "C" void kernel_launch(void* const* d_in, const int* in_sizes, int n_in,
                              void* d_out, int out_size, void* d_ws, size_t ws_size,
                              hipStream_t stream) {
    const float* x    = (const float*)d_in[0];
    const int*   edge = (const int*)d_in[1];
    const int*   batch= (const int*)d_in[2];
    const float* W1   = (const float*)d_in[3];
    const float* b1   = (const float*)d_in[4];
    const float* W2   = (const float*)d_in[5];
    const float* b2   = (const float*)d_in[6];
    const float* Wfc1 = (const float*)d_in[7];
    const float* bfc1 = (const float*)d_in[8];
    const float* Wfc2 = (const float*)d_in[9];
    const float* bfc2 = (const float*)d_in[10];
    float* out = (float*)d_out;

    int N = in_sizes[0] / 128;
    int E = in_sizes[1] / 2;
    const int* src = edge;
    const int* dst = edge + E;

    char* ws = (char*)d_ws;
    size_t off = 0;
    auto alloc = [&](size_t bytes) { void* p = ws + off; off += (bytes + 255) & ~(size_t)255; return p; };
    __half* Ah    = (__half*)alloc((size_t)N * 128 * sizeof(__half));   // gather operand
    float* B      = (float*)alloc((size_t)N * 128 * sizeof(float));     // gather out
    float* dinv   = (float*)alloc((size_t)N * sizeof(float));
    int*   count  = (int*)alloc((size_t)N * sizeof(int));
    int*   tmp    = (int*)alloc((size_t)N * sizeof(int));
    int*   rowptr = (int*)alloc((size_t)(N + 1) * sizeof(int));
    int*   rank   = (int*)alloc((size_t)E * sizeof(int));
    int2*  em     = (int2*)alloc((size_t)E * sizeof(int2));
    int*   bsum   = (int*)alloc(256 * sizeof(int));
    int*   boff   = (int*)alloc(256 * sizeof(int));
    float* pooled = (float*)alloc(64 * 128 * sizeof(float));
    float* cnt    = (float*)alloc(64 * sizeof(float));
    int*   syncv  = (int*)alloc(4 * sizeof(int));
    unsigned short* W1h = (unsigned short*)alloc(16384 * sizeof(short));
    unsigned short* W1l = (unsigned short*)alloc(16384 * sizeof(short));
    unsigned short* W2h = (unsigned short*)alloc(16384 * sizeof(short));
    unsigned short* W2l = (unsigned short*)alloc(16384 * sizeof(short));

    int nb = (N + 255) / 256;               // scan tiles (196)
    int hb = (E + 255) / 256;               // hist blocks (2344)
    int gblocks = (N + 63) / 64;            // gemm blocks (782)
    int ablocks = (N + 3) / 4;              // gather blocks
    int pb = (N + 127) / 128;               // pool blocks (391)
    int zb = (N + 8192 + 64 + 4 + 255) / 256; // zero blocks

    // #1: weight conv + zero everything
    wconv_zero<<<128 + zb, 256, 0, stream>>>(W1, W2, W1h, W1l, W2h, W2l,
                                             count, pooled, cnt, syncv, N);

    // #2: GEMM-1 overlapped with hist+rank (independent)
    fused_hg<<<gblocks + hb, 256, 0, stream>>>(x, W1h, W1l, Ah, N, gblocks,
                                               dst, count, rank, E);

    // #3: whole CSR chain in one kernel (co-resident grid barrier)
    fused_csr<<<nb, 256, 0, stream>>>(count, tmp, bsum, boff, rowptr, dinv,
                                      src, dst, rank, em, syncv, N, E, nb);

    // #4: layer-1 aggregation
    gather_half<<<ablocks, 256, 0, stream>>>(Ah, dinv, b1, rowptr, (const long long*)em, B, N);

    // #5: layer-2 GEMM (relu fused into staging)
    gemm_mfma_relu<<<gblocks, 256, 0, stream>>>(B, W2h, W2l, Ah, N);

    // #6: layer-2 aggregation
    gather_half<<<ablocks, 256, 0, stream>>>(Ah, dinv, b2, rowptr, (const long long*)em, B, N);

    // #7: pool (relu fused) + head
    pool_head<<<pb, 256, 0, stream>>>(B, batch, pooled, cnt,
                                      Wfc1, bfc1, Wfc2, bfc2, out, syncv, N, pb);
}

// Round 3
// 240.281 us; speedup vs baseline: 1.7479x; 1.7479x over previous
//
#include <hip/hip_runtime.h>
#include <hip/hip_fp16.h>

// ---------------------------------------------------------------------------
// GCN pipeline. Round 16:
//  - REVERT round-15 grid-barrier fusions (agent-scope acquire-spin caused a
//    cache-invalidation storm: pool_head 145us). Back to round-14 topology.
//  - NEW gather: 16B/lane vectorized rows (one wave-load = 4 edge rows, 1KB),
//    4 loads in flight (4KB/wave MLP, 2x prior), index-clamp predication,
//    cross-sub shfl_xor reduce. ~90% of nodes finish in one iteration.
//  - RANK TRICK + fused GEMM-1/hist overlap retained.
//  - GEMM: LDS-staged bf16x3 MFMA, frag-ordered W, fp16 out (unchanged)
// ---------------------------------------------------------------------------

typedef short bf16x8 __attribute__((ext_vector_type(8)));
typedef float f32x4  __attribute__((ext_vector_type(4)));

__device__ inline unsigned short f2bf_rne(float f) {
    unsigned u = __float_as_uint(f);
    unsigned r = (u + 0x7fffu + ((u >> 16) & 1u)) >> 16;
    return (unsigned short)r;
}
__device__ inline float bf2f(unsigned short h) {
    return __uint_as_float(((unsigned)h) << 16);
}

// ---- dispatch #1: weight split/transpose + zero(count, pooled, cnt) -----
// frag addr = ((ct*4+ks)*64 + (q*16+nn))*8 + j ; n=ct*16+nn, k=ks*32+q*8+j
__global__ __launch_bounds__(256) void wconv_zero(const float* __restrict__ W1,
                                                  const float* __restrict__ W2,
                                                  unsigned short* __restrict__ W1h,
                                                  unsigned short* __restrict__ W1l,
                                                  unsigned short* __restrict__ W2h,
                                                  unsigned short* __restrict__ W2l,
                                                  int* __restrict__ count,
                                                  float* __restrict__ pooled,
                                                  float* __restrict__ cnt, int N) {
    int tid = threadIdx.x;
    int b = blockIdx.x;
    if (b < 128) {
        int i = b * 256 + tid;               // 0..32767
        const float* W = (i < 16384) ? W1 : W2;
        unsigned short* Wh = (i < 16384) ? W1h : W2h;
        unsigned short* Wl = (i < 16384) ? W1l : W2l;
        int ii = i & 16383;
        int k = ii >> 7, n = ii & 127;
        float v = W[ii];
        unsigned short h = f2bf_rne(v);
        float lo = v - bf2f(h);
        int ct = n >> 4, nn = n & 15, ks = k >> 5, q = (k >> 3) & 3, j = k & 7;
        int oidx = (((ct * 4 + ks) * 64) + (q * 16 + nn)) * 8 + j;
        Wh[oidx] = h;
        Wl[oidx] = f2bf_rne(lo);
    } else {
        int idx = (b - 128) * 256 + tid;
        if (idx < N) count[idx] = 0;
        else if (idx < N + 8192) pooled[idx - N] = 0.f;
        else if (idx < N + 8256) cnt[idx - N - 8192] = 0.f;
    }
}

__global__ __launch_bounds__(256) void scan1_kernel(const int* __restrict__ count,
                                                    int* __restrict__ tmp,
                                                    int* __restrict__ bsum, int N) {
    __shared__ int s[256];
    int tid = threadIdx.x;
    int i = blockIdx.x * 256 + tid;
    int v = (i < N) ? count[i] : 0;
    s[tid] = v;
    __syncthreads();
#pragma unroll
    for (int off = 1; off < 256; off <<= 1) {
        int t = (tid >= off) ? s[tid - off] : 0;
        __syncthreads();
        s[tid] += t;
        __syncthreads();
    }
    if (i < N) tmp[i] = s[tid];
    if (tid == 255) bsum[blockIdx.x] = s[255];
}

// single block: exclusive scan of block sums
__global__ __launch_bounds__(256) void scan2_kernel(const int* __restrict__ bsum,
                                                    int* __restrict__ boff, int nb) {
    __shared__ int s[256];
    int tid = threadIdx.x;
    int v = (tid < nb) ? bsum[tid] : 0;
    s[tid] = v;
    __syncthreads();
#pragma unroll
    for (int off = 1; off < 256; off <<= 1) {
        int t = (tid >= off) ? s[tid - off] : 0;
        __syncthreads();
        s[tid] += t;
        __syncthreads();
    }
    if (tid < nb) boff[tid] = s[tid] - v;   // exclusive
}

// rowptr (exclusive) + dinv
__global__ void finalize_kernel(const int* __restrict__ count, const int* __restrict__ tmp,
                                const int* __restrict__ boff, int* __restrict__ rowptr,
                                float* __restrict__ dinv, int N) {
    int i = blockIdx.x * blockDim.x + threadIdx.x;
    if (i > N) return;
    int ex = (i == 0) ? 0 : tmp[i - 1] + boff[(i - 1) >> 8];
    rowptr[i] = ex;
    if (i < N) dinv[i] = 1.0f / sqrtf((float)count[i] + 1.0f);
}

// atomic-free scatter: position is deterministic from hist's stored rank
__global__ void reorder_kernel(const int* __restrict__ src, const int* __restrict__ dst,
                               const int* __restrict__ rank,
                               const float* __restrict__ dinv,
                               const int* __restrict__ rowptr,
                               int2* __restrict__ em, int E) {
    int e = blockIdx.x * blockDim.x + threadIdx.x;
    if (e < E) {
        int s = src[e], d = dst[e];
        int pos = rowptr[d] + rank[e];
        float norm = dinv[s] * dinv[d];
        em[pos] = make_int2(s, __float_as_int(norm));
    }
}

// ---- GEMM body: OUT_fp16[M,128] = act(X_f32) @ W via bf16x3 MFMA --------
template <bool RELU_IN>
__device__ __forceinline__ void gemm_body(const float* __restrict__ X,
                                          const unsigned short* __restrict__ Wfh,
                                          const unsigned short* __restrict__ Wfl,
                                          __half* __restrict__ OUT, int M, int blk) {
    __shared__ unsigned short Xh[64][136];
    __shared__ unsigned short Xl[64][136];
    int tid = threadIdx.x;
    int w = tid >> 6, l = tid & 63;
    int m0 = blk * 64;

#pragma unroll
    for (int it = 0; it < 8; it++) {
        int i = tid + it * 256;
        int row = i >> 5, c4 = i & 31;
        int grow = m0 + row;
        float4 v = make_float4(0.f, 0.f, 0.f, 0.f);
        if (grow < M) v = *(const float4*)(X + (size_t)grow * 128 + c4 * 4);
        if (RELU_IN) {
            v.x = fmaxf(v.x, 0.f); v.y = fmaxf(v.y, 0.f);
            v.z = fmaxf(v.z, 0.f); v.w = fmaxf(v.w, 0.f);
        }
        float a[4] = {v.x, v.y, v.z, v.w};
        ushort4 hi, lo;
        unsigned short* hp = (unsigned short*)&hi;
        unsigned short* lp = (unsigned short*)&lo;
#pragma unroll
        for (int e = 0; e < 4; e++) {
            unsigned short h = f2bf_rne(a[e]);
            hp[e] = h;
            lp[e] = f2bf_rne(a[e] - bf2f(h));
        }
        *(ushort4*)&Xh[row][c4 * 4] = hi;
        *(ushort4*)&Xl[row][c4 * 4] = lo;
    }
    __syncthreads();

    int q = l >> 4, nn = l & 15;
    f32x4 acc[8];
#pragma unroll
    for (int ct = 0; ct < 8; ct++) acc[ct] = (f32x4){0.f, 0.f, 0.f, 0.f};

#pragma unroll
    for (int ks = 0; ks < 4; ks++) {
        bf16x8 ahi = *(const bf16x8*)&Xh[w * 16 + nn][ks * 32 + q * 8];
        bf16x8 alo = *(const bf16x8*)&Xl[w * 16 + nn][ks * 32 + q * 8];
#pragma unroll
        for (int ct = 0; ct < 8; ct++) {
            size_t fo = ((size_t)(ct * 4 + ks) * 64 + l) * 8;
            bf16x8 bhi = *(const bf16x8*)(Wfh + fo);
            bf16x8 blo = *(const bf16x8*)(Wfl + fo);
            acc[ct] = __builtin_amdgcn_mfma_f32_16x16x32_bf16(ahi, bhi, acc[ct], 0, 0, 0);
            acc[ct] = __builtin_amdgcn_mfma_f32_16x16x32_bf16(alo, bhi, acc[ct], 0, 0, 0);
            acc[ct] = __builtin_amdgcn_mfma_f32_16x16x32_bf16(ahi, blo, acc[ct], 0, 0, 0);
        }
    }
    __syncthreads();   // done with Xh — reuse as fp16 epilogue buffer

#pragma unroll
    for (int r = 0; r < 4; r++) {
        int lrow = w * 16 + q * 4 + r;
#pragma unroll
        for (int ct = 0; ct < 8; ct++) {
            __half hv = __float2half(acc[ct][r]);
            Xh[lrow][ct * 16 + nn] = __half_as_ushort(hv);
        }
    }
    __syncthreads();
#pragma unroll
    for (int t = 0; t < 4; t++) {
        int c = tid + t * 256;
        int row = c >> 4, seg = c & 15;
        int grow = m0 + row;
        if (grow < M) {
            uint4 v = *(uint4*)&Xh[row][seg * 8];
            *(uint4*)((unsigned short*)OUT + (size_t)grow * 128 + seg * 8) = v;
        }
    }
}

// layer-2 GEMM (relu fused in staging)
__global__ __launch_bounds__(256) void gemm_mfma_relu(const float* __restrict__ X,
                                                      const unsigned short* __restrict__ Wfh,
                                                      const unsigned short* __restrict__ Wfl,
                                                      __half* __restrict__ OUT, int M) {
    gemm_body<true>(X, Wfh, Wfl, OUT, M, blockIdx.x);
}

// fat kernel: blocks [0,gblocks) = GEMM-1, blocks [gblocks,..) = hist+rank.
__global__ __launch_bounds__(256) void fused_hg(const float* __restrict__ X,
                                                const unsigned short* __restrict__ Wfh,
                                                const unsigned short* __restrict__ Wfl,
                                                __half* __restrict__ OUT, int M, int gblocks,
                                                const int* __restrict__ dst,
                                                int* __restrict__ count,
                                                int* __restrict__ rank, int E) {
    if ((int)blockIdx.x < gblocks) {
        gemm_body<false>(X, Wfh, Wfl, OUT, M, blockIdx.x);
    } else {
        int e = ((int)blockIdx.x - gblocks) * 256 + (int)threadIdx.x;
        if (e < E) {
            int d = dst[e];
            rank[e] = atomicAdd(&count[d], 1);   // rank within dst bucket
        }
    }
}

// ---- gather: wave/node, 16B/lane rows (4 edges per wave-load) -----------
// lane = sub*16 + cl : sub in [0,4) = edge slot, cl in [0,16) = column group
// each lane accumulates 8 fp32 columns [cl*8, cl*8+8); cross-sub shfl reduce.
__global__ __launch_bounds__(256) void gather_half(const __half* __restrict__ h,
                                                   const float* __restrict__ dinv,
                                                   const float* __restrict__ bias,
                                                   const int* __restrict__ rowptr,
                                                   const long long* __restrict__ em,
                                                   float* __restrict__ B, int N) {
    int n = blockIdx.x * 4 + (threadIdx.x >> 6);
    int lane = threadIdx.x & 63;
    if (n >= N) return;
    int sub = lane >> 4, cl = lane & 15;
    int beg = rowptr[n], end = rowptr[n + 1];
    const unsigned short* hb = (const unsigned short*)h;

    float a0 = 0.f, a1 = 0.f, a2 = 0.f, a3 = 0.f;
    float a4 = 0.f, a5 = 0.f, a6 = 0.f, a7 = 0.f;

    // self-loop term on sub 0 only
    if (sub == 0) {
        float din = dinv[n];
        float sw = din * din;
        uint4 raw = *(const uint4*)(hb + (size_t)n * 128 + cl * 8);
        const __half2* hh = (const __half2*)&raw;
        float2 f0 = __half22float2(hh[0]);
        float2 f1 = __half22float2(hh[1]);
        float2 f2 = __half22float2(hh[2]);
        float2 f3 = __half22float2(hh[3]);
        a0 = fmaf(f0.x, sw, a0); a1 = fmaf(f0.y, sw, a1);
        a2 = fmaf(f1.x, sw, a2); a3 = fmaf(f1.y, sw, a3);
        a4 = fmaf(f2.x, sw, a4); a5 = fmaf(f2.y, sw, a5);
        a6 = fmaf(f3.x, sw, a6); a7 = fmaf(f3.y, sw, a7);
    }

    for (int base = beg; base < end; base += 16) {
        int j0 = base + sub, j1 = j0 + 4, j2 = j0 + 8, j3 = j0 + 12;
        int e1 = end - 1;
        // clamped em loads: all 4 issued back-to-back (predication via norm=0)
        long long v0 = em[min(j0, e1)];
        long long v1 = em[min(j1, e1)];
        long long v2 = em[min(j2, e1)];
        long long v3 = em[min(j3, e1)];
        float n0 = (j0 < end) ? __int_as_float((int)(v0 >> 32)) : 0.f;
        float n1 = (j1 < end) ? __int_as_float((int)(v1 >> 32)) : 0.f;
        float n2 = (j2 < end) ? __int_as_float((int)(v2 >> 32)) : 0.f;
        float n3 = (j3 < end) ? __int_as_float((int)(v3 >> 32)) : 0.f;
        // 4 row loads issued back-to-back (4KB of MLP per wave)
        uint4 r0 = *(const uint4*)(hb + (size_t)(int)v0 * 128 + cl * 8);
        uint4 r1 = *(const uint4*)(hb + (size_t)(int)v1 * 128 + cl * 8);
        uint4 r2 = *(const uint4*)(hb + (size_t)(int)v2 * 128 + cl * 8);
        uint4 r3 = *(const uint4*)(hb + (size_t)(int)v3 * 128 + cl * 8);
        {
            const __half2* hh = (const __half2*)&r0;
            float2 f0 = __half22float2(hh[0]), f1 = __half22float2(hh[1]);
            float2 f2 = __half22float2(hh[2]), f3 = __half22float2(hh[3]);
            a0 = fmaf(f0.x, n0, a0); a1 = fmaf(f0.y, n0, a1);
            a2 = fmaf(f1.x, n0, a2); a3 = fmaf(f1.y, n0, a3);
            a4 = fmaf(f2.x, n0, a4); a5 = fmaf(f2.y, n0, a5);
            a6 = fmaf(f3.x, n0, a6); a7 = fmaf(f3.y, n0, a7);
        }
        {
            const __half2* hh = (const __half2*)&r1;
            float2 f0 = __half22float2(hh[0]), f1 = __half22float2(hh[1]);
            float2 f2 = __half22float2(hh[2]), f3 = __half22float2(hh[3]);
            a0 = fmaf(f0.x, n1, a0); a1 = fmaf(f0.y, n1, a1);
            a2 = fmaf(f1.x, n1, a2); a3 = fmaf(f1.y, n1, a3);
            a4 = fmaf(f2.x, n1, a4); a5 = fmaf(f2.y, n1, a5);
            a6 = fmaf(f3.x, n1, a6); a7 = fmaf(f3.y, n1, a7);
        }
        {
            const __half2* hh = (const __half2*)&r2;
            float2 f0 = __half22float2(hh[0]), f1 = __half22float2(hh[1]);
            float2 f2 = __half22float2(hh[2]), f3 = __half22float2(hh[3]);
            a0 = fmaf(f0.x, n2, a0); a1 = fmaf(f0.y, n2, a1);
            a2 = fmaf(f1.x, n2, a2); a3 = fmaf(f1.y, n2, a3);
            a4 = fmaf(f2.x, n2, a4); a5 = fmaf(f2.y, n2, a5);
            a6 = fmaf(f3.x, n2, a6); a7 = fmaf(f3.y, n2, a7);
        }
        {
            const __half2* hh = (const __half2*)&r3;
            float2 f0 = __half22float2(hh[0]), f1 = __half22float2(hh[1]);
            float2 f2 = __half22float2(hh[2]), f3 = __half22float2(hh[3]);
            a0 = fmaf(f0.x, n3, a0); a1 = fmaf(f0.y, n3, a1);
            a2 = fmaf(f1.x, n3, a2); a3 = fmaf(f1.y, n3, a3);
            a4 = fmaf(f2.x, n3, a4); a5 = fmaf(f2.y, n3, a5);
            a6 = fmaf(f3.x, n3, a6); a7 = fmaf(f3.y, n3, a7);
        }
    }

    // combine the 4 edge slots: lanes {cl, cl+16, cl+32, cl+48} hold partials
#pragma unroll
    for (int m = 16; m < 64; m <<= 1) {
        a0 += __shfl_xor(a0, m, 64); a1 += __shfl_xor(a1, m, 64);
        a2 += __shfl_xor(a2, m, 64); a3 += __shfl_xor(a3, m, 64);
        a4 += __shfl_xor(a4, m, 64); a5 += __shfl_xor(a5, m, 64);
        a6 += __shfl_xor(a6, m, 64); a7 += __shfl_xor(a7, m, 64);
    }

    if (sub == 0) {
        float4 o0, o1;
        o0.x = a0 + bias[cl * 8 + 0]; o0.y = a1 + bias[cl * 8 + 1];
        o0.z = a2 + bias[cl * 8 + 2]; o0.w = a3 + bias[cl * 8 + 3];
        o1.x = a4 + bias[cl * 8 + 4]; o1.y = a5 + bias[cl * 8 + 5];
        o1.z = a6 + bias[cl * 8 + 6]; o1.w = a7 + bias[cl * 8 + 7];
        *(float4*)(B + (size_t)n * 128 + cl * 8) = o0;
        *(float4*)(B + (size_t)n * 128 + cl * 8 + 4) = o1;
    }
}

// ---- pool: batch sorted -> run-length, atomics only at transitions ------
__global__ __launch_bounds__(256) void pool_kernel(const float* __restrict__ B,
                                                   const int* __restrict__ batch,
                                                   float* pooled, float* cnt, int N) {
    int c = threadIdx.x & 127;
    int half = threadIdx.x >> 7;
    int n0 = blockIdx.x * 128;
    float acc = 0.f, cacc = 0.f;
    int curg = -1;
    for (int i = half; i < 128; i += 2) {
        int n = n0 + i;
        if (n >= N) break;
        int g = batch[n];
        float v = fmaxf(B[(size_t)n * 128 + c], 0.f);
        if (g != curg) {
            if (curg >= 0) {
                atomicAdd(&pooled[curg * 128 + c], acc);
                if (c == 0) atomicAdd(&cnt[curg], cacc);
            }
            curg = g; acc = 0.f; cacc = 0.f;
        }
        acc += v; cacc += 1.f;
    }
    if (curg >= 0) {
        atomicAdd(&pooled[curg * 128 + c], acc);
        if (c == 0) atomicAdd(&cnt[curg], cacc);
    }
}

// ---- head: one wave per graph ------------------------------------------
__global__ __launch_bounds__(64) void head_kernel(const float* __restrict__ pooled,
                                                  const float* __restrict__ cnt,
                                                  const float* __restrict__ Wfc1,
                                                  const float* __restrict__ bfc1,
                                                  const float* __restrict__ Wfc2,
                                                  const float* __restrict__ bfc2,
                                                  float* __restrict__ out) {
    __shared__ float mean[128];
    int g = blockIdx.x;
    int t = threadIdx.x;
    float inv = 1.0f / fmaxf(cnt[g], 1.0f);
    mean[t] = pooled[g * 128 + t] * inv;
    mean[t + 64] = pooled[g * 128 + t + 64] * inv;
    __syncthreads();
    float s = bfc1[t];
#pragma unroll 4
    for (int k = 0; k < 128; k++) s = fmaf(mean[k], Wfc1[k * 64 + t], s);
    float p = fmaxf(s, 0.f) * Wfc2[t];
#pragma unroll
    for (int o = 32; o > 0; o >>= 1) p += __shfl_down(p, o, 64);
    if (t == 0) out[g] = p + bfc2[0];
}

extern "C" void kernel_launch(void* const* d_in, const int* in_sizes, int n_in,
                              void* d_out, int out_size, void* d_ws, size_t ws_size,
                              hipStream_t stream) {
    const float* x    = (const float*)d_in[0];
    const int*   edge = (const int*)d_in[1];
    const int*   batch= (const int*)d_in[2];
    const float* W1   = (const float*)d_in[3];
    const float* b1   = (const float*)d_in[4];
    const float* W2   = (const float*)d_in[5];
    const float* b2   = (const float*)d_in[6];
    const float* Wfc1 = (const float*)d_in[7];
    const float* bfc1 = (const float*)d_in[8];
    const float* Wfc2 = (const float*)d_in[9];
    const float* bfc2 = (const float*)d_in[10];
    float* out = (float*)d_out;

    int N = in_sizes[0] / 128;
    int E = in_sizes[1] / 2;
    const int* src = edge;
    const int* dst = edge + E;

    char* ws = (char*)d_ws;
    size_t off = 0;
    auto alloc = [&](size_t bytes) { void* p = ws + off; off += (bytes + 255) & ~(size_t)255; return p; };
    __half* Ah    = (__half*)alloc((size_t)N * 128 * sizeof(__half));   // gather operand
    float* B      = (float*)alloc((size_t)N * 128 * sizeof(float));     // gather out
    float* dinv   = (float*)alloc((size_t)N * sizeof(float));
    int*   count  = (int*)alloc((size_t)N * sizeof(int));
    int*   tmp    = (int*)alloc((size_t)N * sizeof(int));
    int*   rowptr = (int*)alloc((size_t)(N + 1) * sizeof(int));
    int*   rank   = (int*)alloc((size_t)E * sizeof(int));
    int2*  em     = (int2*)alloc((size_t)E * sizeof(int2));
    int*   bsum   = (int*)alloc(256 * sizeof(int));
    int*   boff   = (int*)alloc(256 * sizeof(int));
    float* pooled = (float*)alloc(64 * 128 * sizeof(float));
    float* cnt    = (float*)alloc(64 * sizeof(float));
    unsigned short* W1h = (unsigned short*)alloc(16384 * sizeof(short));
    unsigned short* W1l = (unsigned short*)alloc(16384 * sizeof(short));
    unsigned short* W2h = (unsigned short*)alloc(16384 * sizeof(short));
    unsigned short* W2l = (unsigned short*)alloc(16384 * sizeof(short));

    int nb = (N + 255) / 256;               // scan1 blocks (196)
    int hb = (E + 255) / 256;               // hist blocks (2344)
    int gblocks = (N + 63) / 64;            // gemm blocks (782)
    int ablocks = (N + 3) / 4;              // gather blocks
    int zb = (N + 8256 + 255) / 256;        // zero blocks (count+pooled+cnt)

    // #1: weight conv + zero everything
    wconv_zero<<<128 + zb, 256, 0, stream>>>(W1, W2, W1h, W1l, W2h, W2l,
                                             count, pooled, cnt, N);

    // #2: GEMM-1 overlapped with hist+rank (independent)
    fused_hg<<<gblocks + hb, 256, 0, stream>>>(x, W1h, W1l, Ah, N, gblocks,
                                               dst, count, rank, E);

    // #3-#6: CSR finish + atomic-free scatter
    scan1_kernel<<<nb, 256, 0, stream>>>(count, tmp, bsum, N);
    scan2_kernel<<<1, 256, 0, stream>>>(bsum, boff, nb);
    finalize_kernel<<<(N + 256) / 256, 256, 0, stream>>>(count, tmp, boff, rowptr, dinv, N);
    reorder_kernel<<<hb, 256, 0, stream>>>(src, dst, rank, dinv, rowptr, em, E);

    // Layer 1 aggregation
    gather_half<<<ablocks, 256, 0, stream>>>(Ah, dinv, b1, rowptr, (const long long*)em, B, N);

    // Layer 2 (relu fused into GEMM staging)
    gemm_mfma_relu<<<gblocks, 256, 0, stream>>>(B, W2h, W2l, Ah, N);
    gather_half<<<ablocks, 256, 0, stream>>>(Ah, dinv, b2, rowptr, (const long long*)em, B, N);

    // Pool (relu fused) + head
    pool_kernel<<<(N + 127) / 128, 256, 0, stream>>>(B, batch, pooled, cnt, N);
    head_kernel<<<64, 64, 0, stream>>>(pooled, cnt, Wfc1, bfc1, Wfc2, bfc2, out);
}